// Round 1
// baseline (633.521 us; speedup 1.0000x reference)
//
#include <hip/hip_runtime.h>
#include <hip/hip_fp16.h>

typedef _Float16 f16;
typedef __attribute__((ext_vector_type(4))) _Float16 f16x4;
typedef __attribute__((ext_vector_type(8))) _Float16 f16x8;
typedef __attribute__((ext_vector_type(4))) float f32x4;

#define BATCH 8
#define SEQ 1024
#define DMODEL 1024
#define NHEAD 16
#define DHEAD 64

// ============================================================================
// GEMM (B-transposed): C[m,n] = sum_k A[m,k] * W[n,k] + bias[n]
// A,W fp32 in (converted to fp16 during LDS staging), fp32 accumulate/out.
// 128x128 tile, BK=32, 4 waves (2x2), 4x4 16x16x32 MFMA fragments per wave.
// ============================================================================
__global__ __launch_bounds__(256) void gemm_bt(const float* __restrict__ A,
                                               const float* __restrict__ W,
                                               const float* __restrict__ bias,
                                               float* __restrict__ C,
                                               int M, int N, int K) {
  __shared__ f16 As[128 * 32];
  __shared__ f16 Bs[128 * 32];
  const int t = threadIdx.x;
  const int lane = t & 63, wid = t >> 6;
  const int wm = wid >> 1, wn = wid & 1;
  const int row_l = lane & 15, kgrp = lane >> 4;
  const int m0 = blockIdx.x * 128, n0 = blockIdx.y * 128;
  f32x4 acc[4][4] = {};

  for (int k0 = 0; k0 < K; k0 += 32) {
    // stage 128x32 fp32 -> fp16 for both tiles; 256 thr x 4 rounds x float4
    #pragma unroll
    for (int r = 0; r < 4; ++r) {
      int idx = r * 256 + t;
      int row = idx >> 3, col = (idx & 7) << 2;
      float4 va = *(const float4*)&A[(size_t)(m0 + row) * K + k0 + col];
      f16x4 ha; ha[0] = (f16)va.x; ha[1] = (f16)va.y; ha[2] = (f16)va.z; ha[3] = (f16)va.w;
      *(f16x4*)&As[row * 32 + col] = ha;
      float4 vb = *(const float4*)&W[(size_t)(n0 + row) * K + k0 + col];
      f16x4 hb; hb[0] = (f16)vb.x; hb[1] = (f16)vb.y; hb[2] = (f16)vb.z; hb[3] = (f16)vb.w;
      *(f16x4*)&Bs[row * 32 + col] = hb;
    }
    __syncthreads();
    f16x8 af[4], bf[4];
    #pragma unroll
    for (int i = 0; i < 4; i++) af[i] = *(const f16x8*)&As[(wm * 64 + i * 16 + row_l) * 32 + kgrp * 8];
    #pragma unroll
    for (int j = 0; j < 4; j++) bf[j] = *(const f16x8*)&Bs[(wn * 64 + j * 16 + row_l) * 32 + kgrp * 8];
    #pragma unroll
    for (int i = 0; i < 4; i++)
      #pragma unroll
      for (int j = 0; j < 4; j++)
        acc[i][j] = __builtin_amdgcn_mfma_f32_16x16x32_f16(af[i], bf[j], acc[i][j], 0, 0, 0);
    __syncthreads();
  }

  #pragma unroll
  for (int i = 0; i < 4; i++) {
    int m = m0 + wm * 64 + i * 16 + kgrp * 4;
    #pragma unroll
    for (int j = 0; j < 4; j++) {
      int n = n0 + wn * 64 + j * 16 + row_l;
      float bb = bias[n];
      #pragma unroll
      for (int r = 0; r < 4; r++)
        C[(size_t)(m + r) * N + n] = acc[i][j][r] + bb;
    }
  }
}

// ============================================================================
// RoPE over full d_model + cast fp32 -> fp16.
// out[d]      = x[d]*cos[d]   - x[d+512]*sin[d]       (d < 512)
// out[d+512]  = x[d+512]*cos[d+512] + x[d]*sin[d+512]
// one thread = 4 pair-columns
// ============================================================================
__global__ __launch_bounds__(256) void rope_cast(const float* __restrict__ X,
                                                 const float* __restrict__ cosb,
                                                 const float* __restrict__ sinb,
                                                 f16* __restrict__ out) {
  int idx = blockIdx.x * 256 + threadIdx.x;      // total B*S*128
  int row = idx >> 7;                             // b*S + s
  int d4 = (idx & 127) << 2;                      // 0..508 step 4
  int s = row & (SEQ - 1);
  const float* xr = X + (size_t)row * DMODEL;
  float4 x1 = *(const float4*)&xr[d4];
  float4 x2 = *(const float4*)&xr[d4 + 512];
  float4 c1 = *(const float4*)&cosb[(size_t)s * DMODEL + d4];
  float4 s1 = *(const float4*)&sinb[(size_t)s * DMODEL + d4];
  float4 c2 = *(const float4*)&cosb[(size_t)s * DMODEL + d4 + 512];
  float4 s2 = *(const float4*)&sinb[(size_t)s * DMODEL + d4 + 512];
  f16x4 o1, o2;
  o1[0] = (f16)(x1.x * c1.x - x2.x * s1.x);
  o1[1] = (f16)(x1.y * c1.y - x2.y * s1.y);
  o1[2] = (f16)(x1.z * c1.z - x2.z * s1.z);
  o1[3] = (f16)(x1.w * c1.w - x2.w * s1.w);
  o2[0] = (f16)(x2.x * c2.x + x1.x * s2.x);
  o2[1] = (f16)(x2.y * c2.y + x1.y * s2.y);
  o2[2] = (f16)(x2.z * c2.z + x1.z * s2.z);
  o2[3] = (f16)(x2.w * c2.w + x1.w * s2.w);
  f16* orow = out + (size_t)row * DMODEL;
  *(f16x4*)&orow[d4] = o1;
  *(f16x4*)&orow[d4 + 512] = o2;
}

// ============================================================================
// V transpose + cast: Vt[b][d][s] = Vp[b][s][d]   (f32 -> f16), 64x64 LDS tiles
// ============================================================================
__global__ __launch_bounds__(256) void transcast_v(const float* __restrict__ X,
                                                   f16* __restrict__ Vt) {
  int bz = blockIdx.x;            // B * (S/64) * (D/64) = 2048
  int dt = bz & 15;
  int st = (bz >> 4) & 15;
  int b = bz >> 8;
  int s0 = st * 64, d0 = dt * 64;
  __shared__ f16 tile[64][68];
  int t = threadIdx.x;
  int tr = t >> 4, tc = t & 15;
  #pragma unroll
  for (int i = 0; i < 4; i++) {
    int s_loc = tr + i * 16;
    float4 v = *(const float4*)&X[((size_t)(b * SEQ + s0 + s_loc)) * DMODEL + d0 + tc * 4];
    f16x4 hv; hv[0] = (f16)v.x; hv[1] = (f16)v.y; hv[2] = (f16)v.z; hv[3] = (f16)v.w;
    *(f16x4*)&tile[s_loc][tc * 4] = hv;
  }
  __syncthreads();
  #pragma unroll
  for (int i = 0; i < 4; i++) {
    int d_loc = tr + i * 16;
    f16x4 hv;
    #pragma unroll
    for (int j = 0; j < 4; j++) hv[j] = tile[tc * 4 + j][d_loc];
    *(f16x4*)&Vt[((size_t)(b * DMODEL + d0 + d_loc)) * SEQ + s0 + tc * 4] = hv;
  }
}

// ============================================================================
// Flash attention: grid = B*H*(S/64); block = 4 waves; each wave owns 16 q-rows.
// kv blocks of 32. scores = QK^T/8 + mask[b,kv] + sigmoid(prior[h])*shortm[q,kv]
// online softmax (m,l per q-row), PV accumulated fp32. concat out fp32.
// ============================================================================
__global__ __launch_bounds__(256) void attn(const f16* __restrict__ Q,
                                            const f16* __restrict__ K,
                                            const f16* __restrict__ Vt,
                                            const float* __restrict__ mask,
                                            const float* __restrict__ shortm,
                                            const float* __restrict__ prior,
                                            float* __restrict__ out) {
  int bz = blockIdx.x;
  int qb = bz & 15;            // S/64 = 16 q-blocks
  int bh = bz >> 4;
  int b = bh >> 4;             // H = 16
  int h = bh & 15;
  int t = threadIdx.x, lane = t & 63, wid = t >> 6;
  int row_l = lane & 15, kgrp = lane >> 4;
  float pscale = 1.0f / (1.0f + __expf(-prior[h]));

  int qrow0 = qb * 64 + wid * 16;
  const f16* Qb = Q + ((size_t)(b * SEQ + qrow0)) * DMODEL + h * DHEAD;
  const f16* Kb = K + ((size_t)b * SEQ) * DMODEL + h * DHEAD;
  const f16* Vb = Vt + ((size_t)(b * DMODEL + h * DHEAD)) * SEQ;
  const float* maskb = mask + b * SEQ;

  f16x8 aq[2];
  aq[0] = *(const f16x8*)&Qb[row_l * DMODEL + kgrp * 8];
  aq[1] = *(const f16x8*)&Qb[row_l * DMODEL + 32 + kgrp * 8];

  __shared__ f16 Plds[4][16][40];   // 40: +8 pad -> stride 80B = 5x16B, conflict-light
  float mrow[4], lrow[4];
  f32x4 acco[4] = {};
  #pragma unroll
  for (int r = 0; r < 4; r++) { mrow[r] = -INFINITY; lrow[r] = 0.0f; }

  for (int kb = 0; kb < SEQ; kb += 32) {
    // --- scores: 16 q x 32 kv ---
    f32x4 sc[2] = {};
    #pragma unroll
    for (int half = 0; half < 2; half++) {
      const f16* kr = &Kb[(size_t)(kb + half * 16 + row_l) * DMODEL];
      f16x8 k0 = *(const f16x8*)&kr[kgrp * 8];
      f16x8 k1 = *(const f16x8*)&kr[32 + kgrp * 8];
      sc[half] = __builtin_amdgcn_mfma_f32_16x16x32_f16(aq[0], k0, sc[half], 0, 0, 0);
      sc[half] = __builtin_amdgcn_mfma_f32_16x16x32_f16(aq[1], k1, sc[half], 0, 0, 0);
    }
    float s[2][4];
    #pragma unroll
    for (int half = 0; half < 2; half++) {
      int kv = kb + half * 16 + row_l;
      float mk = maskb[kv];
      #pragma unroll
      for (int r = 0; r < 4; r++) {
        int qg = qrow0 + kgrp * 4 + r;
        s[half][r] = sc[half][r] * 0.125f + mk + pscale * shortm[(size_t)qg * SEQ + kv];
      }
    }
    // --- online softmax ---
    float mnew[4], fs[4];
    #pragma unroll
    for (int r = 0; r < 4; r++) {
      float mx = fmaxf(s[0][r], s[1][r]);
      #pragma unroll
      for (int off = 1; off < 16; off <<= 1) mx = fmaxf(mx, __shfl_xor(mx, off));
      mnew[r] = fmaxf(mrow[r], mx);
      fs[r] = __expf(mrow[r] - mnew[r]);
      mrow[r] = mnew[r];
    }
    float p[2][4];
    #pragma unroll
    for (int half = 0; half < 2; half++)
      #pragma unroll
      for (int r = 0; r < 4; r++) p[half][r] = __expf(s[half][r] - mnew[r]);
    #pragma unroll
    for (int r = 0; r < 4; r++) {
      float rs = p[0][r] + p[1][r];
      #pragma unroll
      for (int off = 1; off < 16; off <<= 1) rs += __shfl_xor(rs, off);
      lrow[r] = lrow[r] * fs[r] + rs;
    }
    #pragma unroll
    for (int t2 = 0; t2 < 4; t2++)
      #pragma unroll
      for (int r = 0; r < 4; r++) acco[t2][r] *= fs[r];
    // --- P -> LDS (score layout -> A-fragment layout) ---
    #pragma unroll
    for (int half = 0; half < 2; half++)
      #pragma unroll
      for (int r = 0; r < 4; r++)
        Plds[wid][kgrp * 4 + r][half * 16 + row_l] = (f16)p[half][r];
    f16x8 pa = *(const f16x8*)&Plds[wid][row_l][kgrp * 8];
    // --- PV ---
    #pragma unroll
    for (int t2 = 0; t2 < 4; t2++) {
      f16x8 bv = *(const f16x8*)&Vb[(size_t)(t2 * 16 + row_l) * SEQ + kb + kgrp * 8];
      acco[t2] = __builtin_amdgcn_mfma_f32_16x16x32_f16(pa, bv, acco[t2], 0, 0, 0);
    }
  }
  // --- epilogue: out[b, q, h*64+dv] = acc/l ---
  #pragma unroll
  for (int t2 = 0; t2 < 4; t2++) {
    #pragma unroll
    for (int r = 0; r < 4; r++) {
      int qg = qrow0 + kgrp * 4 + r;
      out[((size_t)(b * SEQ + qg)) * DMODEL + h * DHEAD + t2 * 16 + row_l] =
          acco[t2][r] / lrow[r];
    }
  }
}

// ============================================================================
extern "C" void kernel_launch(void* const* d_in, const int* in_sizes, int n_in,
                              void* d_out, int out_size, void* d_ws, size_t ws_size,
                              hipStream_t stream) {
  const float* q      = (const float*)d_in[0];
  const float* k      = (const float*)d_in[1];
  const float* v      = (const float*)d_in[2];
  const float* cosb   = (const float*)d_in[3];
  const float* sinb   = (const float*)d_in[4];
  const float* mask   = (const float*)d_in[5];
  const float* shortm = (const float*)d_in[6];
  const float* Wq     = (const float*)d_in[7];
  const float* bq     = (const float*)d_in[8];
  const float* Wk     = (const float*)d_in[9];
  const float* bk     = (const float*)d_in[10];
  const float* Wv     = (const float*)d_in[11];
  const float* bv     = (const float*)d_in[12];
  const float* Wo     = (const float*)d_in[13];
  const float* bo     = (const float*)d_in[14];
  const float* prior  = (const float*)d_in[15];
  float* outp = (float*)d_out;

  const size_t M = (size_t)BATCH * SEQ;           // 8192
  char* w = (char*)d_ws;
  float* proj = (float*)w;   w += M * DMODEL * sizeof(float);   // 33.5 MB (reused)
  f16* qro    = (f16*)w;     w += M * DMODEL * sizeof(f16);     // 16.8 MB
  f16* kro    = (f16*)w;     w += M * DMODEL * sizeof(f16);
  f16* vt     = (f16*)w;     w += M * DMODEL * sizeof(f16);
  float* cat  = (float*)w;   w += M * DMODEL * sizeof(float);   // 33.5 MB

  dim3 gemm_grid(M / 128, DMODEL / 128);   // 64 x 8

  // Q projection + RoPE
  gemm_bt<<<gemm_grid, 256, 0, stream>>>(q, Wq, bq, proj, (int)M, DMODEL, DMODEL);
  rope_cast<<<(int)(M * 128 / 256), 256, 0, stream>>>(proj, cosb, sinb, qro);
  // K projection + RoPE
  gemm_bt<<<gemm_grid, 256, 0, stream>>>(k, Wk, bk, proj, (int)M, DMODEL, DMODEL);
  rope_cast<<<(int)(M * 128 / 256), 256, 0, stream>>>(proj, cosb, sinb, kro);
  // V projection + transpose
  gemm_bt<<<gemm_grid, 256, 0, stream>>>(v, Wv, bv, proj, (int)M, DMODEL, DMODEL);
  transcast_v<<<BATCH * 16 * 16, 256, 0, stream>>>(proj, vt);
  // attention
  attn<<<BATCH * NHEAD * (SEQ / 64), 256, 0, stream>>>(qro, kro, vt, mask, shortm, prior, cat);
  // output projection -> d_out
  gemm_bt<<<gemm_grid, 256, 0, stream>>>(cat, Wo, bo, outp, (int)M, DMODEL, DMODEL);
}

// Round 2
// 442.560 us; speedup vs baseline: 1.4315x; 1.4315x over previous
//
#include <hip/hip_runtime.h>
#include <hip/hip_fp16.h>

typedef _Float16 f16;
typedef __attribute__((ext_vector_type(4))) _Float16 f16x4;
typedef __attribute__((ext_vector_type(8))) _Float16 f16x8;
typedef __attribute__((ext_vector_type(4))) float f32x4;

#define BATCH 8
#define SEQ 1024
#define DMODEL 1024
#define NHEAD 16
#define DHEAD 64

// async global->LDS, 16B per lane; LDS dest is wave-uniform base + lane*16
#define GLD16(gptr, lptr)                                                        \
  __builtin_amdgcn_global_load_lds(                                              \
      (const __attribute__((address_space(1))) void*)(gptr),                     \
      (__attribute__((address_space(3))) void*)(lptr), 16, 0, 0)

// ============================================================================
// cast fp32 -> fp16 for q,k,v and the 4 weight matrices into one flat buffer
// layout: [q | k | v | Wq | Wk | Wv | Wo]
// ============================================================================
#define NQKV 8388608u   // B*S*D
#define NW   1048576u   // D*D
__global__ __launch_bounds__(256) void cast_all(
    const float* __restrict__ q, const float* __restrict__ k,
    const float* __restrict__ v, const float* __restrict__ wq,
    const float* __restrict__ wk, const float* __restrict__ wv,
    const float* __restrict__ wo, f16* __restrict__ dst) {
  size_t i8 = ((size_t)blockIdx.x * 256 + threadIdx.x) * 8;
  const float* src; size_t off;
  if      (i8 < (size_t)NQKV)            { src = q;  off = 0; }
  else if (i8 < 2ull * NQKV)             { src = k;  off = NQKV; }
  else if (i8 < 3ull * NQKV)             { src = v;  off = 2ull * NQKV; }
  else if (i8 < 3ull * NQKV + NW)        { src = wq; off = 3ull * NQKV; }
  else if (i8 < 3ull * NQKV + 2ull * NW) { src = wk; off = 3ull * NQKV + NW; }
  else if (i8 < 3ull * NQKV + 3ull * NW) { src = wv; off = 3ull * NQKV + 2ull * NW; }
  else                                   { src = wo; off = 3ull * NQKV + 3ull * NW; }
  float4 a = *(const float4*)&src[i8 - off];
  float4 b = *(const float4*)&src[i8 - off + 4];
  f16x8 h;
  h[0] = (f16)a.x; h[1] = (f16)a.y; h[2] = (f16)a.z; h[3] = (f16)a.w;
  h[4] = (f16)b.x; h[5] = (f16)b.y; h[6] = (f16)b.z; h[7] = (f16)b.w;
  *(f16x8*)&dst[i8] = h;
}

// ============================================================================
// fp16 GEMM (B-transposed): C[m,n] = sum_k A[m,k]*W[n,k] + bias[n]
// m97 structure: 128x128 tile, BK=32, global_load_lds width-16 staging,
// 4 waves (2x2), 4x4 16x16x32 MFMA fragments per wave, fp32 accumulate.
// ============================================================================
template <bool OUT16>
__global__ __launch_bounds__(256) void gemm16(const f16* __restrict__ A,
                                              const f16* __restrict__ W,
                                              const float* __restrict__ bias,
                                              void* __restrict__ Cv,
                                              int M, int N, int K) {
  __shared__ f16 As[128 * 32];
  __shared__ f16 Bs[128 * 32];
  const int t = threadIdx.x;
  const int lane = t & 63, wid = t >> 6;
  const int wm = wid >> 1, wn = wid & 1;
  const int row_l = lane & 15, kgrp = lane >> 4;
  const int m0 = blockIdx.x * 128, n0 = blockIdx.y * 128;
  f32x4 acc[4][4] = {};

  // per-thread staging coords: linear slot s = rr*256 + t; row = s/4, col8 = s&3
  const int srow = t >> 2, scol = (t & 3) * 8;

  for (int k0 = 0; k0 < K; k0 += 32) {
    #pragma unroll
    for (int rr = 0; rr < 2; ++rr) {
      int row = srow + rr * 64;
      char* abase = (char*)As + (rr * 256 + wid * 64) * 16;
      char* bbase = (char*)Bs + (rr * 256 + wid * 64) * 16;
      GLD16(&A[(size_t)(m0 + row) * K + k0 + scol], abase);
      GLD16(&W[(size_t)(n0 + row) * K + k0 + scol], bbase);
    }
    __syncthreads();
    f16x8 af[4], bf[4];
    #pragma unroll
    for (int i = 0; i < 4; i++) af[i] = *(const f16x8*)&As[(wm * 64 + i * 16 + row_l) * 32 + kgrp * 8];
    #pragma unroll
    for (int j = 0; j < 4; j++) bf[j] = *(const f16x8*)&Bs[(wn * 64 + j * 16 + row_l) * 32 + kgrp * 8];
    #pragma unroll
    for (int i = 0; i < 4; i++)
      #pragma unroll
      for (int j = 0; j < 4; j++)
        acc[i][j] = __builtin_amdgcn_mfma_f32_16x16x32_f16(af[i], bf[j], acc[i][j], 0, 0, 0);
    __syncthreads();
  }

  #pragma unroll
  for (int i = 0; i < 4; i++) {
    int m = m0 + wm * 64 + i * 16 + kgrp * 4;
    #pragma unroll
    for (int j = 0; j < 4; j++) {
      int n = n0 + wn * 64 + j * 16 + row_l;
      float bb = bias[n];
      #pragma unroll
      for (int r = 0; r < 4; r++) {
        float val = acc[i][j][r] + bb;
        if (OUT16) ((f16*)Cv)[(size_t)(m + r) * N + n] = (f16)val;
        else       ((float*)Cv)[(size_t)(m + r) * N + n] = val;
      }
    }
  }
}

// ============================================================================
// RoPE over full d_model (fp16 in -> fp16 out, fp32 math, fp32 cos/sin)
// ============================================================================
__global__ __launch_bounds__(256) void rope16(const f16* __restrict__ X,
                                              const float* __restrict__ cosb,
                                              const float* __restrict__ sinb,
                                              f16* __restrict__ out) {
  int idx = blockIdx.x * 256 + threadIdx.x;   // B*S*128 threads total
  int row = idx >> 7;
  int d4 = (idx & 127) << 2;
  int s = row & (SEQ - 1);
  const f16* xr = X + (size_t)row * DMODEL;
  f16x4 x1 = *(const f16x4*)&xr[d4];
  f16x4 x2 = *(const f16x4*)&xr[d4 + 512];
  float4 c1 = *(const float4*)&cosb[(size_t)s * DMODEL + d4];
  float4 s1 = *(const float4*)&sinb[(size_t)s * DMODEL + d4];
  float4 c2 = *(const float4*)&cosb[(size_t)s * DMODEL + d4 + 512];
  float4 s2 = *(const float4*)&sinb[(size_t)s * DMODEL + d4 + 512];
  f16x4 o1, o2;
  o1[0] = (f16)((float)x1[0] * c1.x - (float)x2[0] * s1.x);
  o1[1] = (f16)((float)x1[1] * c1.y - (float)x2[1] * s1.y);
  o1[2] = (f16)((float)x1[2] * c1.z - (float)x2[2] * s1.z);
  o1[3] = (f16)((float)x1[3] * c1.w - (float)x2[3] * s1.w);
  o2[0] = (f16)((float)x2[0] * c2.x + (float)x1[0] * s2.x);
  o2[1] = (f16)((float)x2[1] * c2.y + (float)x1[1] * s2.y);
  o2[2] = (f16)((float)x2[2] * c2.z + (float)x1[2] * s2.z);
  o2[3] = (f16)((float)x2[3] * c2.w + (float)x1[3] * s2.w);
  f16* orow = out + (size_t)row * DMODEL;
  *(f16x4*)&orow[d4] = o1;
  *(f16x4*)&orow[d4 + 512] = o2;
}

// ============================================================================
// V transpose (fp16): Vt[b][d][s] = Vp[b][s][d], 64x64 LDS tiles
// ============================================================================
__global__ __launch_bounds__(256) void transv16(const f16* __restrict__ X,
                                                f16* __restrict__ Vt) {
  int bz = blockIdx.x;            // B * 16 * 16 = 2048
  int dt = bz & 15;
  int st = (bz >> 4) & 15;
  int b = bz >> 8;
  int s0 = st * 64, d0 = dt * 64;
  __shared__ f16 tile[64][68];
  int t = threadIdx.x;
  int tr = t >> 4, tc = t & 15;
  #pragma unroll
  for (int i = 0; i < 4; i++) {
    int s_loc = tr + i * 16;
    f16x4 v = *(const f16x4*)&X[((size_t)(b * SEQ + s0 + s_loc)) * DMODEL + d0 + tc * 4];
    *(f16x4*)&tile[s_loc][tc * 4] = v;
  }
  __syncthreads();
  #pragma unroll
  for (int i = 0; i < 4; i++) {
    int d_loc = tr + i * 16;
    f16x4 hv;
    #pragma unroll
    for (int j = 0; j < 4; j++) hv[j] = tile[tc * 4 + j][d_loc];
    *(f16x4*)&Vt[((size_t)(b * DMODEL + d0 + d_loc)) * SEQ + s0 + tc * 4] = hv;
  }
}

// ============================================================================
// Flash attention v2: grid = B*H*(S/64); 4 waves, wave owns 16 q-rows.
// kv-block 64; K/V tiles LDS-staged via global_load_lds with XOR slot-swizzle
// (pre-swizzled global source, linear LDS dest, swizzled ds_read_b128).
// Softmax in base-2 domain. fp16 out.
// ============================================================================
__global__ __launch_bounds__(256) void attn2(const f16* __restrict__ Q,
                                             const f16* __restrict__ K,
                                             const f16* __restrict__ Vt,
                                             const float* __restrict__ mask,
                                             const float* __restrict__ shortm,
                                             const float* __restrict__ prior,
                                             f16* __restrict__ out) {
  const float LOG2E = 1.44269504f;
  int bz = blockIdx.x;
  int qb = bz & 15, bh = bz >> 4;
  int b = bh >> 4, h = bh & 15;
  int t = threadIdx.x, lane = t & 63, wid = t >> 6;
  int row_l = lane & 15, kgrp = lane >> 4;
  float psc = LOG2E / (1.0f + __expf(-prior[h]));   // sigmoid(prior)*log2e
  const float qscale = 0.125f * LOG2E;

  int qrow0 = qb * 64 + wid * 16;
  const f16* Qb = Q + ((size_t)(b * SEQ + qrow0)) * DMODEL + h * DHEAD;
  const f16* Kb = K + ((size_t)b * SEQ) * DMODEL + h * DHEAD;
  const f16* Vb = Vt + ((size_t)(b * DMODEL + h * DHEAD)) * SEQ;
  const float* maskb = mask + (size_t)b * SEQ;
  const float* smb = shortm + (size_t)qrow0 * SEQ;

  f16x8 aq[2];
  aq[0] = *(const f16x8*)&Qb[row_l * DMODEL + kgrp * 8];
  aq[1] = *(const f16x8*)&Qb[row_l * DMODEL + 32 + kgrp * 8];

  __shared__ f16 Ks[64 * 64];
  __shared__ f16 Vs[64 * 64];
  __shared__ f16 Pl[4][16 * 64];
  f16* Pw = &Pl[wid][0];

  float mrow[4], lrow[4];
  f32x4 acco[4] = {};
  #pragma unroll
  for (int r = 0; r < 4; r++) { mrow[r] = -3.0e38f; lrow[r] = 0.0f; }

  // staging coords: linear slot s = rr*256 + t -> row = s/8, slot8 = t&7
  const int slot8 = t & 7;

  for (int kb = 0; kb < SEQ; kb += 64) {
    // --- stage K,V 64x64 tiles (swizzled source -> linear LDS) ---
    #pragma unroll
    for (int rr = 0; rr < 2; ++rr) {
      int row = (t >> 3) + rr * 32;
      int gc = ((slot8 ^ (row & 7)) * 8);
      char* kbase = (char*)Ks + (rr * 256 + wid * 64) * 16;
      char* vbase = (char*)Vs + (rr * 256 + wid * 64) * 16;
      GLD16(&Kb[(size_t)(kb + row) * DMODEL + gc], kbase);
      GLD16(&Vb[(size_t)row * SEQ + kb + gc], vbase);
    }
    __syncthreads();

    // --- QK^T: 16q x 64kv ---
    f32x4 sc[4];
    #pragma unroll
    for (int hh = 0; hh < 4; ++hh) {
      int kr = hh * 16 + row_l;
      int sw = kr & 7;
      f16x8 k0 = *(const f16x8*)&Ks[kr * 64 + ((kgrp ^ sw) * 8)];
      f16x8 k1 = *(const f16x8*)&Ks[kr * 64 + (((4 + kgrp) ^ sw) * 8)];
      f32x4 z = {};
      z = __builtin_amdgcn_mfma_f32_16x16x32_f16(aq[0], k0, z, 0, 0, 0);
      z = __builtin_amdgcn_mfma_f32_16x16x32_f16(aq[1], k1, z, 0, 0, 0);
      sc[hh] = z;
    }

    // --- scale + mask + prior bias (base-2 domain) ---
    float s[4][4];
    #pragma unroll
    for (int hh = 0; hh < 4; ++hh) {
      int kv = kb + hh * 16 + row_l;
      float mk = maskb[kv] * LOG2E;
      #pragma unroll
      for (int r = 0; r < 4; r++)
        s[hh][r] = sc[hh][r] * qscale + mk + psc * smb[(size_t)(kgrp * 4 + r) * SEQ + kv];
    }

    // --- online softmax ---
    float fs[4], mnew[4];
    #pragma unroll
    for (int r = 0; r < 4; r++) {
      float mx = fmaxf(fmaxf(s[0][r], s[1][r]), fmaxf(s[2][r], s[3][r]));
      #pragma unroll
      for (int off = 1; off < 16; off <<= 1) mx = fmaxf(mx, __shfl_xor(mx, off));
      mnew[r] = fmaxf(mrow[r], mx);
      fs[r] = exp2f(mrow[r] - mnew[r]);
      mrow[r] = mnew[r];
    }
    float p[4][4];
    #pragma unroll
    for (int hh = 0; hh < 4; ++hh)
      #pragma unroll
      for (int r = 0; r < 4; r++) p[hh][r] = exp2f(s[hh][r] - mnew[r]);
    #pragma unroll
    for (int r = 0; r < 4; r++) {
      float rs = (p[0][r] + p[1][r]) + (p[2][r] + p[3][r]);
      #pragma unroll
      for (int off = 1; off < 16; off <<= 1) rs += __shfl_xor(rs, off);
      lrow[r] = lrow[r] * fs[r] + rs;
    }
    #pragma unroll
    for (int t2 = 0; t2 < 4; t2++)
      #pragma unroll
      for (int r = 0; r < 4; r++) acco[t2][r] *= fs[r];

    // --- P -> LDS (swizzled slots), wave-private ---
    #pragma unroll
    for (int hh = 0; hh < 4; ++hh)
      #pragma unroll
      for (int r = 0; r < 4; r++) {
        int qr = kgrp * 4 + r;
        int col = hh * 16 + row_l;
        int slot = col >> 3;
        Pw[qr * 64 + ((slot ^ (qr & 7)) * 8) + (col & 7)] = (f16)p[hh][r];
      }
    f16x8 pa[2];
    {
      int sw = row_l & 7;
      pa[0] = *(const f16x8*)&Pw[row_l * 64 + ((kgrp ^ sw) * 8)];
      pa[1] = *(const f16x8*)&Pw[row_l * 64 + (((4 + kgrp) ^ sw) * 8)];
    }

    // --- PV: 16q x 64dv ---
    #pragma unroll
    for (int t2 = 0; t2 < 4; t2++) {
      int vr = t2 * 16 + row_l;
      int sw = vr & 7;
      f16x8 b0 = *(const f16x8*)&Vs[vr * 64 + ((kgrp ^ sw) * 8)];
      f16x8 b1 = *(const f16x8*)&Vs[vr * 64 + (((4 + kgrp) ^ sw) * 8)];
      acco[t2] = __builtin_amdgcn_mfma_f32_16x16x32_f16(pa[0], b0, acco[t2], 0, 0, 0);
      acco[t2] = __builtin_amdgcn_mfma_f32_16x16x32_f16(pa[1], b1, acco[t2], 0, 0, 0);
    }
    __syncthreads();
  }

  // --- epilogue ---
  #pragma unroll
  for (int r = 0; r < 4; r++) {
    int qg = qrow0 + kgrp * 4 + r;
    float inv = 1.0f / lrow[r];
    #pragma unroll
    for (int t2 = 0; t2 < 4; t2++)
      out[((size_t)(b * SEQ + qg)) * DMODEL + h * DHEAD + t2 * 16 + row_l] =
          (f16)(acco[t2][r] * inv);
  }
}

// ============================================================================
extern "C" void kernel_launch(void* const* d_in, const int* in_sizes, int n_in,
                              void* d_out, int out_size, void* d_ws, size_t ws_size,
                              hipStream_t stream) {
  const float* q      = (const float*)d_in[0];
  const float* k      = (const float*)d_in[1];
  const float* v      = (const float*)d_in[2];
  const float* cosb   = (const float*)d_in[3];
  const float* sinb   = (const float*)d_in[4];
  const float* mask   = (const float*)d_in[5];
  const float* shortm = (const float*)d_in[6];
  const float* Wq     = (const float*)d_in[7];
  const float* bq     = (const float*)d_in[8];
  const float* Wk     = (const float*)d_in[9];
  const float* bk     = (const float*)d_in[10];
  const float* Wv     = (const float*)d_in[11];
  const float* bv     = (const float*)d_in[12];
  const float* Wo     = (const float*)d_in[13];
  const float* bo     = (const float*)d_in[14];
  const float* prior  = (const float*)d_in[15];
  float* outp = (float*)d_out;

  const size_t M = (size_t)BATCH * SEQ;           // 8192
  f16* ws16 = (f16*)d_ws;
  // casted flat buffer [q | k | v | Wq | Wk | Wv | Wo]
  f16* qf  = ws16;                                  // 8.4M elems (dead after qproj)
  f16* kf  = ws16 + (size_t)NQKV;                   // (dead after kproj)
  f16* vf  = ws16 + 2ull * NQKV;
  f16* Wqf = ws16 + 3ull * NQKV;
  f16* Wkf = Wqf + NW;
  f16* Wvf = Wkf + NW;
  f16* Wof = Wvf + NW;
  f16* proj = ws16 + 3ull * NQKV + 4ull * NW;       // 8.4M
  f16* qro  = proj + NQKV;                          // 8.4M
  f16* kro  = qro + NQKV;                           // 8.4M
  f16* vt   = qf;                                   // alias: qf dead after qproj
  f16* cat  = kf;                                   // alias: kf dead after kproj

  dim3 gemm_grid(M / 128, DMODEL / 128);            // 64 x 8

  cast_all<<<(3u * NQKV + 4u * NW) / 8 / 256, 256, 0, stream>>>(q, k, v, Wq, Wk, Wv, Wo, ws16);

  // Q projection + RoPE
  gemm16<true><<<gemm_grid, 256, 0, stream>>>(qf, Wqf, bq, proj, (int)M, DMODEL, DMODEL);
  rope16<<<(int)(M * 128 / 256), 256, 0, stream>>>(proj, cosb, sinb, qro);
  // K projection + RoPE
  gemm16<true><<<gemm_grid, 256, 0, stream>>>(kf, Wkf, bk, proj, (int)M, DMODEL, DMODEL);
  rope16<<<(int)(M * 128 / 256), 256, 0, stream>>>(proj, cosb, sinb, kro);
  // V projection + transpose
  gemm16<true><<<gemm_grid, 256, 0, stream>>>(vf, Wvf, bv, proj, (int)M, DMODEL, DMODEL);
  transv16<<<BATCH * 16 * 16, 256, 0, stream>>>(proj, vt);
  // attention
  attn2<<<BATCH * NHEAD * (SEQ / 64), 256, 0, stream>>>(qro, kro, vt, mask, shortm, prior, cat);
  // output projection -> d_out (fp32)
  gemm16<false><<<gemm_grid, 256, 0, stream>>>(cat, Wof, bo, outp, (int)M, DMODEL, DMODEL);
}

// Round 3
// 424.877 us; speedup vs baseline: 1.4911x; 1.0416x over previous
//
#include <hip/hip_runtime.h>
#include <hip/hip_fp16.h>

typedef _Float16 f16;
typedef __attribute__((ext_vector_type(4))) _Float16 f16x4;
typedef __attribute__((ext_vector_type(8))) _Float16 f16x8;
typedef __attribute__((ext_vector_type(4))) float f32x4;
typedef __attribute__((ext_vector_type(4))) unsigned int u32x4;

#define BATCH 8
#define SEQ 1024
#define DMODEL 1024
#define NHEAD 16
#define DHEAD 64
#define QSCALE 0.1803368801f   /* 0.125 * log2(e) */
#define L2E 1.44269504f

// async global->LDS, 16B per lane; LDS dest is wave-uniform base + lane*16
#define GLD16(gptr, lptr)                                                        \
  __builtin_amdgcn_global_load_lds(                                              \
      (const __attribute__((address_space(1))) void*)(gptr),                     \
      (__attribute__((address_space(3))) void*)(lptr), 16, 0, 0)

#define NQKV 8388608u   // B*S*D
#define NW   1048576u   // D*D

__device__ inline unsigned pk2(float a, float b) {
  unsigned short ha = __builtin_bit_cast(unsigned short, (f16)a);
  unsigned short hb = __builtin_bit_cast(unsigned short, (f16)b);
  return ((unsigned)hb << 16) | (unsigned)ha;
}

// ============================================================================
// cast fp32 -> fp16: [q | k | v | Wq | Wk | Wv | Wo] into one flat buffer
// ============================================================================
__global__ __launch_bounds__(256) void cast_all(
    const float* __restrict__ q, const float* __restrict__ k,
    const float* __restrict__ v, const float* __restrict__ wq,
    const float* __restrict__ wk, const float* __restrict__ wv,
    const float* __restrict__ wo, f16* __restrict__ dst) {
  size_t i8 = ((size_t)blockIdx.x * 256 + threadIdx.x) * 8;
  const float* src; size_t off;
  if      (i8 < (size_t)NQKV)            { src = q;  off = 0; }
  else if (i8 < 2ull * NQKV)             { src = k;  off = NQKV; }
  else if (i8 < 3ull * NQKV)             { src = v;  off = 2ull * NQKV; }
  else if (i8 < 3ull * NQKV + NW)        { src = wq; off = 3ull * NQKV; }
  else if (i8 < 3ull * NQKV + 2ull * NW) { src = wk; off = 3ull * NQKV + NW; }
  else if (i8 < 3ull * NQKV + 3ull * NW) { src = wv; off = 3ull * NQKV + 2ull * NW; }
  else                                   { src = wo; off = 3ull * NQKV + 3ull * NW; }
  float4 a = *(const float4*)&src[i8 - off];
  float4 b = *(const float4*)&src[i8 - off + 4];
  f16x8 h;
  h[0] = (f16)a.x; h[1] = (f16)a.y; h[2] = (f16)a.z; h[3] = (f16)a.w;
  h[4] = (f16)b.x; h[5] = (f16)b.y; h[6] = (f16)b.z; h[7] = (f16)b.w;
  *(f16x8*)&dst[i8] = h;
}

// ============================================================================
// Fused QKV projection GEMM: for section which = n0>>10 (0=q,1=k,2=v):
//   out_which[m, n&1023] = sum_k A_which[m,k]*W[n,k] + bias_which[n&1023]
// A sections are contiguous [qf|kf|vf]; W sections contiguous [Wq|Wk|Wv].
// 128x128 tile, BK=32, global_load_lds staging, 4 waves, fp32 accum, f16 out.
// ============================================================================
__global__ __launch_bounds__(256) void gemm_qkv(const f16* __restrict__ Abase,
                                                const f16* __restrict__ Wqkv,
                                                const float* __restrict__ bq,
                                                const float* __restrict__ bk,
                                                const float* __restrict__ bv,
                                                f16* __restrict__ qp,
                                                f16* __restrict__ kp,
                                                f16* __restrict__ vp) {
  const int K = DMODEL;
  __shared__ f16 As[128 * 32];
  __shared__ f16 Bs[128 * 32];
  const int t = threadIdx.x;
  const int lane = t & 63, wid = t >> 6;
  const int wm = wid >> 1, wn = wid & 1;
  const int row_l = lane & 15, kgrp = lane >> 4;
  const int m0 = blockIdx.x * 128, n0 = blockIdx.y * 128;
  const int which = n0 >> 10;
  const f16* A = Abase + (size_t)which * NQKV;
  const float* bias = which == 0 ? bq : (which == 1 ? bk : bv);
  f16* outp = which == 0 ? qp : (which == 1 ? kp : vp);
  const int nloc0 = n0 & 1023;
  f32x4 acc[4][4] = {};

  const int srow = t >> 2, scol = (t & 3) * 8;

  for (int k0 = 0; k0 < K; k0 += 32) {
    #pragma unroll
    for (int rr = 0; rr < 2; ++rr) {
      int row = srow + rr * 64;
      char* abase = (char*)As + (rr * 256 + wid * 64) * 16;
      char* bbase = (char*)Bs + (rr * 256 + wid * 64) * 16;
      GLD16(&A[(size_t)(m0 + row) * K + k0 + scol], abase);
      GLD16(&Wqkv[(size_t)(n0 + row) * K + k0 + scol], bbase);
    }
    __syncthreads();
    f16x8 af[4], bf[4];
    #pragma unroll
    for (int i = 0; i < 4; i++) af[i] = *(const f16x8*)&As[(wm * 64 + i * 16 + row_l) * 32 + kgrp * 8];
    #pragma unroll
    for (int j = 0; j < 4; j++) bf[j] = *(const f16x8*)&Bs[(wn * 64 + j * 16 + row_l) * 32 + kgrp * 8];
    #pragma unroll
    for (int i = 0; i < 4; i++)
      #pragma unroll
      for (int j = 0; j < 4; j++)
        acc[i][j] = __builtin_amdgcn_mfma_f32_16x16x32_f16(af[i], bf[j], acc[i][j], 0, 0, 0);
    __syncthreads();
  }

  #pragma unroll
  for (int i = 0; i < 4; i++) {
    int m = m0 + wm * 64 + i * 16 + kgrp * 4;
    #pragma unroll
    for (int j = 0; j < 4; j++) {
      int n = nloc0 + wn * 64 + j * 16 + row_l;
      float bb = bias[n];
      #pragma unroll
      for (int r = 0; r < 4; r++)
        outp[(size_t)(m + r) * DMODEL + n] = (f16)(acc[i][j][r] + bb);
    }
  }
}

// ============================================================================
// Generic fp16 GEMM (B-transposed), fp32 out — used for the O projection.
// ============================================================================
__global__ __launch_bounds__(256) void gemm16f(const f16* __restrict__ A,
                                               const f16* __restrict__ W,
                                               const float* __restrict__ bias,
                                               float* __restrict__ C,
                                               int M, int N, int K) {
  __shared__ f16 As[128 * 32];
  __shared__ f16 Bs[128 * 32];
  const int t = threadIdx.x;
  const int lane = t & 63, wid = t >> 6;
  const int wm = wid >> 1, wn = wid & 1;
  const int row_l = lane & 15, kgrp = lane >> 4;
  const int m0 = blockIdx.x * 128, n0 = blockIdx.y * 128;
  f32x4 acc[4][4] = {};
  const int srow = t >> 2, scol = (t & 3) * 8;

  for (int k0 = 0; k0 < K; k0 += 32) {
    #pragma unroll
    for (int rr = 0; rr < 2; ++rr) {
      int row = srow + rr * 64;
      char* abase = (char*)As + (rr * 256 + wid * 64) * 16;
      char* bbase = (char*)Bs + (rr * 256 + wid * 64) * 16;
      GLD16(&A[(size_t)(m0 + row) * K + k0 + scol], abase);
      GLD16(&W[(size_t)(n0 + row) * K + k0 + scol], bbase);
    }
    __syncthreads();
    f16x8 af[4], bf[4];
    #pragma unroll
    for (int i = 0; i < 4; i++) af[i] = *(const f16x8*)&As[(wm * 64 + i * 16 + row_l) * 32 + kgrp * 8];
    #pragma unroll
    for (int j = 0; j < 4; j++) bf[j] = *(const f16x8*)&Bs[(wn * 64 + j * 16 + row_l) * 32 + kgrp * 8];
    #pragma unroll
    for (int i = 0; i < 4; i++)
      #pragma unroll
      for (int j = 0; j < 4; j++)
        acc[i][j] = __builtin_amdgcn_mfma_f32_16x16x32_f16(af[i], bf[j], acc[i][j], 0, 0, 0);
    __syncthreads();
  }

  #pragma unroll
  for (int i = 0; i < 4; i++) {
    int m = m0 + wm * 64 + i * 16 + kgrp * 4;
    #pragma unroll
    for (int j = 0; j < 4; j++) {
      int n = n0 + wn * 64 + j * 16 + row_l;
      float bb = bias[n];
      #pragma unroll
      for (int r = 0; r < 4; r++)
        C[(size_t)(m + r) * N + n] = acc[i][j][r] + bb;
    }
  }
}

// ============================================================================
// RoPE for q (scaled by QSCALE) and k in one launch. fp16 in/out, fp32 math.
// ============================================================================
__global__ __launch_bounds__(256) void rope2(const f16* __restrict__ Xq,
                                             const f16* __restrict__ Xk,
                                             const float* __restrict__ cosb,
                                             const float* __restrict__ sinb,
                                             f16* __restrict__ oq,
                                             f16* __restrict__ ok) {
  int idx = blockIdx.x * 256 + threadIdx.x;      // 0 .. 2*B*S*128
  const int HALFN = BATCH * SEQ * 128;
  bool isq = idx < HALFN;
  if (!isq) idx -= HALFN;
  const f16* X = isq ? Xq : Xk;
  f16* out = isq ? oq : ok;
  float scale = isq ? QSCALE : 1.0f;
  int row = idx >> 7;
  int d4 = (idx & 127) << 2;
  int s = row & (SEQ - 1);
  const f16* xr = X + (size_t)row * DMODEL;
  f16x4 x1 = *(const f16x4*)&xr[d4];
  f16x4 x2 = *(const f16x4*)&xr[d4 + 512];
  float4 c1 = *(const float4*)&cosb[(size_t)s * DMODEL + d4];
  float4 s1 = *(const float4*)&sinb[(size_t)s * DMODEL + d4];
  float4 c2 = *(const float4*)&cosb[(size_t)s * DMODEL + d4 + 512];
  float4 s2 = *(const float4*)&sinb[(size_t)s * DMODEL + d4 + 512];
  f16x4 o1, o2;
  o1[0] = (f16)(scale * ((float)x1[0] * c1.x - (float)x2[0] * s1.x));
  o1[1] = (f16)(scale * ((float)x1[1] * c1.y - (float)x2[1] * s1.y));
  o1[2] = (f16)(scale * ((float)x1[2] * c1.z - (float)x2[2] * s1.z));
  o1[3] = (f16)(scale * ((float)x1[3] * c1.w - (float)x2[3] * s1.w));
  o2[0] = (f16)(scale * ((float)x2[0] * c2.x + (float)x1[0] * s2.x));
  o2[1] = (f16)(scale * ((float)x2[1] * c2.y + (float)x1[1] * s2.y));
  o2[2] = (f16)(scale * ((float)x2[2] * c2.z + (float)x1[2] * s2.z));
  o2[3] = (f16)(scale * ((float)x2[3] * c2.w + (float)x1[3] * s2.w));
  f16* orow = out + (size_t)row * DMODEL;
  *(f16x4*)&orow[d4] = o1;
  *(f16x4*)&orow[d4 + 512] = o2;
}

// ============================================================================
// V transpose (fp16): Vt[b][d][s] = Vp[b][s][d], 64x64 LDS tiles
// ============================================================================
__global__ __launch_bounds__(256) void transv16(const f16* __restrict__ X,
                                                f16* __restrict__ Vt) {
  int bz = blockIdx.x;            // B * 16 * 16 = 2048
  int dt = bz & 15;
  int st = (bz >> 4) & 15;
  int b = bz >> 8;
  int s0 = st * 64, d0 = dt * 64;
  __shared__ f16 tile[64][68];
  int t = threadIdx.x;
  int tr = t >> 4, tc = t & 15;
  #pragma unroll
  for (int i = 0; i < 4; i++) {
    int s_loc = tr + i * 16;
    f16x4 v = *(const f16x4*)&X[((size_t)(b * SEQ + s0 + s_loc)) * DMODEL + d0 + tc * 4];
    *(f16x4*)&tile[s_loc][tc * 4] = v;
  }
  __syncthreads();
  #pragma unroll
  for (int i = 0; i < 4; i++) {
    int d_loc = tr + i * 16;
    f16x4 hv;
    #pragma unroll
    for (int j = 0; j < 4; j++) hv[j] = tile[tc * 4 + j][d_loc];
    *(f16x4*)&Vt[((size_t)(b * DMODEL + d0 + d_loc)) * SEQ + s0 + tc * 4] = hv;
  }
}

// ============================================================================
// Flash attention v3 — swapped operands (lane owns one q-column):
//   S^T = mfma(K, Q)  -> lane(l15,g) holds S[kv=g*4+r+16hh][q=l15]
//   O^T = mfma(V^T, P^T) -> lane holds O[dv=t2*16+g*4+r][q=l15]
// m/l per-lane scalars; P redistributed in-register via ds_bpermute.
// K/V double-buffered LDS via global_load_lds, XOR slot-swizzle.
// Q pre-scaled by 0.125*log2e (folded in rope2); softmax in base-2.
// ============================================================================
__global__ __launch_bounds__(256) void attn3(const f16* __restrict__ Q,
                                             const f16* __restrict__ K,
                                             const f16* __restrict__ Vt,
                                             const float* __restrict__ mask,
                                             const float* __restrict__ shortm,
                                             const float* __restrict__ prior,
                                             f16* __restrict__ out) {
  int bz = blockIdx.x;
  int qb = bz & 15, bh = bz >> 4;
  int b = bh >> 4, h = bh & 15;
  int t = threadIdx.x, lane = t & 63, wid = t >> 6;
  int l15 = lane & 15, g = lane >> 4;
  float psc2 = L2E / (1.0f + __expf(-prior[h]));   // sigmoid(prior)*log2e

  const int qrow0 = qb * 64;
  const int qrow = qrow0 + wid * 16 + l15;         // this lane's q
  const f16* Qr = Q + ((size_t)(b * SEQ + qrow)) * DMODEL + h * DHEAD;
  const f16* Kb = K + ((size_t)b * SEQ) * DMODEL + h * DHEAD;
  const f16* Vb = Vt + ((size_t)(b * DMODEL + h * DHEAD)) * SEQ;
  const float* maskb = mask + (size_t)b * SEQ;
  const float* smr = shortm + (size_t)qrow * SEQ;

  // Q as B-frag: col=q=l15, k=d=g*8+j
  f16x8 aq0 = *(const f16x8*)&Qr[g * 8];
  f16x8 aq1 = *(const f16x8*)&Qr[32 + g * 8];

  __shared__ f16 Ks[2][64 * 64];
  __shared__ f16 Vs[2][64 * 64];

  float mrow = -3.0e38f, lrow = 0.0f;
  f32x4 acco[4] = {};

  // staging coords
  const int slot8 = t & 7;
  const int srow = t >> 3;                  // 0..31 (wave wid covers rows wid*8..+7)
  const int gc = ((slot8 ^ (srow & 7)) * 8);
  // bpermute coords
  const int s0 = (g & 1) * 2;
  const int addr0 = (l15 + 16 * s0) * 4;
  const int addr1 = addr0 + 64;
  const bool lowg = (g < 2);
  const int sw = l15 & 7;

#define STAGE(tile, buf)                                                          \
  {                                                                               \
    int kb2 = (tile) * 64;                                                        \
    _Pragma("unroll")                                                             \
    for (int rr = 0; rr < 2; ++rr) {                                              \
      int row = srow + rr * 32;                                                   \
      char* kdst = (char*)&Ks[buf][0] + rr * 4096 + wid * 1024;                   \
      char* vdst = (char*)&Vs[buf][0] + rr * 4096 + wid * 1024;                   \
      GLD16(&Kb[(size_t)(kb2 + row) * DMODEL + gc], kdst);                        \
      GLD16(&Vb[(size_t)row * SEQ + kb2 + gc], vdst);                             \
    }                                                                             \
  }

  STAGE(0, 0);
  __syncthreads();

  for (int it = 0; it < 16; ++it) {
    int cur = it & 1;
    if (it < 15) STAGE(it + 1, cur ^ 1);
    int kb = it * 64;
    const f16* ks = &Ks[cur][0];
    const f16* vs = &Vs[cur][0];

    // --- QK^T (swapped): sc[hh] = S^T[kv=g*4+r+16hh][q=l15] ---
    f32x4 sc[4];
    #pragma unroll
    for (int hh = 0; hh < 4; ++hh) {
      int kr = l15 + 16 * hh;
      f16x8 kf0 = *(const f16x8*)&ks[kr * 64 + ((g ^ sw) * 8)];
      f16x8 kf1 = *(const f16x8*)&ks[kr * 64 + (((4 + g) ^ sw) * 8)];
      f32x4 z = {};
      z = __builtin_amdgcn_mfma_f32_16x16x32_f16(kf0, aq0, z, 0, 0, 0);
      z = __builtin_amdgcn_mfma_f32_16x16x32_f16(kf1, aq1, z, 0, 0, 0);
      sc[hh] = z;
    }

    // --- bias: s = sc + mask*log2e + psc2*shortm (vectorized float4 loads) ---
    float s[4][4];
    #pragma unroll
    for (int hh = 0; hh < 4; ++hh) {
      int kv = kb + hh * 16 + g * 4;
      float4 mk = *(const float4*)&maskb[kv];
      float4 sm = *(const float4*)&smr[kv];
      s[hh][0] = fmaf(L2E, mk.x, fmaf(psc2, sm.x, sc[hh][0]));
      s[hh][1] = fmaf(L2E, mk.y, fmaf(psc2, sm.y, sc[hh][1]));
      s[hh][2] = fmaf(L2E, mk.z, fmaf(psc2, sm.z, sc[hh][2]));
      s[hh][3] = fmaf(L2E, mk.w, fmaf(psc2, sm.w, sc[hh][3]));
    }

    // --- online softmax (per-lane scalar m/l) ---
    float pmax = fmaxf(fmaxf(fmaxf(s[0][0], s[0][1]), fmaxf(s[0][2], s[0][3])),
                       fmaxf(fmaxf(s[1][0], s[1][1]), fmaxf(s[1][2], s[1][3])));
    pmax = fmaxf(pmax, fmaxf(fmaxf(fmaxf(s[2][0], s[2][1]), fmaxf(s[2][2], s[2][3])),
                             fmaxf(fmaxf(s[3][0], s[3][1]), fmaxf(s[3][2], s[3][3]))));
    pmax = fmaxf(pmax, __shfl_xor(pmax, 16));
    pmax = fmaxf(pmax, __shfl_xor(pmax, 32));
    if (__any(pmax > mrow)) {
      float mnew = fmaxf(mrow, pmax);
      float fs = exp2f(mrow - mnew);
      lrow *= fs;
      #pragma unroll
      for (int t2 = 0; t2 < 4; ++t2)
        #pragma unroll
        for (int r = 0; r < 4; ++r) acco[t2][r] *= fs;
      mrow = mnew;
    }
    float p[4][4];
    #pragma unroll
    for (int hh = 0; hh < 4; ++hh)
      #pragma unroll
      for (int r = 0; r < 4; ++r) p[hh][r] = exp2f(s[hh][r] - mrow);
    float rs = ((p[0][0] + p[0][1]) + (p[0][2] + p[0][3])) +
               ((p[1][0] + p[1][1]) + (p[1][2] + p[1][3])) +
               ((p[2][0] + p[2][1]) + (p[2][2] + p[2][3])) +
               ((p[3][0] + p[3][1]) + (p[3][2] + p[3][3]));
    rs += __shfl_xor(rs, 16);
    rs += __shfl_xor(rs, 32);
    lrow += rs;

    // --- pack P to f16 + in-register redistribution to B-frag layout ---
    unsigned cfr[2][4];
    #pragma unroll
    for (int half = 0; half < 2; ++half) {
      unsigned a0 = pk2(p[half * 2][0], p[half * 2][1]);
      unsigned a1 = pk2(p[half * 2][2], p[half * 2][3]);
      unsigned b0 = pk2(p[half * 2 + 1][0], p[half * 2 + 1][1]);
      unsigned b1 = pk2(p[half * 2 + 1][2], p[half * 2 + 1][3]);
      int ta0 = __builtin_amdgcn_ds_bpermute(addr0, (int)a0);
      int ta1 = __builtin_amdgcn_ds_bpermute(addr0, (int)a1);
      int tb0 = __builtin_amdgcn_ds_bpermute(addr0, (int)b0);
      int tb1 = __builtin_amdgcn_ds_bpermute(addr0, (int)b1);
      int ua0 = __builtin_amdgcn_ds_bpermute(addr1, (int)a0);
      int ua1 = __builtin_amdgcn_ds_bpermute(addr1, (int)a1);
      int ub0 = __builtin_amdgcn_ds_bpermute(addr1, (int)b0);
      int ub1 = __builtin_amdgcn_ds_bpermute(addr1, (int)b1);
      cfr[half][0] = (unsigned)(lowg ? ta0 : tb0);
      cfr[half][1] = (unsigned)(lowg ? ta1 : tb1);
      cfr[half][2] = (unsigned)(lowg ? ua0 : ub0);
      cfr[half][3] = (unsigned)(lowg ? ua1 : ub1);
    }

    // --- PV (swapped): acco[t2] covers dv = t2*16 + g*4 + r ---
    #pragma unroll
    for (int half = 0; half < 2; ++half) {
      u32x4 cc; cc[0] = cfr[half][0]; cc[1] = cfr[half][1];
      cc[2] = cfr[half][2]; cc[3] = cfr[half][3];
      f16x8 pf = __builtin_bit_cast(f16x8, cc);
      #pragma unroll
      for (int t2 = 0; t2 < 4; ++t2) {
        int vr = t2 * 16 + l15;
        f16x8 vf = *(const f16x8*)&vs[vr * 64 + (((half * 4 + g) ^ sw) * 8)];
        acco[t2] = __builtin_amdgcn_mfma_f32_16x16x32_f16(vf, pf, acco[t2], 0, 0, 0);
      }
    }
    __syncthreads();
  }

  // --- epilogue: O^T -> LDS transpose (swizzled) -> coalesced f16 store ---
  float inv = 1.0f / lrow;
  f16* Pw = &Ks[0][0] + wid * 1024;   // wave-private 16q x 64dv slice
  #pragma unroll
  for (int t2 = 0; t2 < 4; ++t2) {
    f16x4 o;
    #pragma unroll
    for (int r = 0; r < 4; ++r) o[r] = (f16)(acco[t2][r] * inv);
    int sl = t2 * 4 + g;              // 8B slot = dv>>2
    int s16 = sl >> 1, p8 = sl & 1;
    int swz = s16 ^ sw;
    *(f16x4*)&Pw[l15 * 64 + swz * 8 + p8 * 4] = o;
  }
  __syncthreads();
  int rq = lane >> 3;                 // 0..7
  int cs = lane & 7;                  // real 16B slot (dv block)
  #pragma unroll
  for (int half = 0; half < 2; ++half) {
    int q_loc = rq + half * 8;
    int swz = cs ^ (q_loc & 7);
    f16x8 vv = *(const f16x8*)&Pw[q_loc * 64 + swz * 8];
    int qg = qrow0 + wid * 16 + q_loc;
    *(f16x8*)&out[((size_t)(b * SEQ + qg)) * DMODEL + h * DHEAD + cs * 8] = vv;
  }
#undef STAGE
}

// ============================================================================
extern "C" void kernel_launch(void* const* d_in, const int* in_sizes, int n_in,
                              void* d_out, int out_size, void* d_ws, size_t ws_size,
                              hipStream_t stream) {
  const float* q      = (const float*)d_in[0];
  const float* k      = (const float*)d_in[1];
  const float* v      = (const float*)d_in[2];
  const float* cosb   = (const float*)d_in[3];
  const float* sinb   = (const float*)d_in[4];
  const float* mask   = (const float*)d_in[5];
  const float* shortm = (const float*)d_in[6];
  const float* Wq     = (const float*)d_in[7];
  const float* bq     = (const float*)d_in[8];
  const float* Wk     = (const float*)d_in[9];
  const float* bk     = (const float*)d_in[10];
  const float* Wv     = (const float*)d_in[11];
  const float* bv     = (const float*)d_in[12];
  const float* Wo     = (const float*)d_in[13];
  const float* bo     = (const float*)d_in[14];
  const float* prior  = (const float*)d_in[15];
  float* outp = (float*)d_out;

  const size_t M = (size_t)BATCH * SEQ;             // 8192
  f16* ws16 = (f16*)d_ws;
  f16* qf   = ws16;                                 // casted inputs (contiguous)
  f16* kf   = ws16 + (size_t)NQKV;
  f16* vf   = ws16 + 2ull * NQKV;
  f16* Wqkv = ws16 + 3ull * NQKV;                   // [Wq|Wk|Wv] contiguous
  f16* Wof  = Wqkv + 3ull * NW;
  f16* qp   = ws16 + 3ull * NQKV + 4ull * NW;       // projection outputs
  f16* kp   = qp + NQKV;
  f16* vp   = kp + NQKV;
  // aliases (sources dead by the time these are written)
  f16* qro = qf;
  f16* kro = kf;
  f16* vt  = vf;
  f16* cat = qp;

  cast_all<<<(3u * NQKV + 4u * NW) / 8 / 256, 256, 0, stream>>>(q, k, v, Wq, Wk, Wv, Wo, ws16);

  dim3 qkv_grid(M / 128, 3 * DMODEL / 128);         // 64 x 24
  gemm_qkv<<<qkv_grid, 256, 0, stream>>>(qf, Wqkv, bq, bk, bv, qp, kp, vp);

  rope2<<<2 * (int)(M * 128 / 256), 256, 0, stream>>>(qp, kp, cosb, sinb, qro, kro);
  transv16<<<BATCH * 16 * 16, 256, 0, stream>>>(vp, vt);

  attn3<<<BATCH * NHEAD * (SEQ / 64), 256, 0, stream>>>(qro, kro, vt, mask, shortm, prior, cat);

  dim3 o_grid(M / 128, DMODEL / 128);               // 64 x 8
  gemm16f<<<o_grid, 256, 0, stream>>>(cat, Wof, bo, outp, (int)M, DMODEL, DMODEL);
}

// Round 4
// 395.027 us; speedup vs baseline: 1.6037x; 1.0756x over previous
//
#include <hip/hip_runtime.h>
#include <hip/hip_fp16.h>

typedef _Float16 f16;
typedef __attribute__((ext_vector_type(4))) _Float16 f16x4;
typedef __attribute__((ext_vector_type(8))) _Float16 f16x8;
typedef __attribute__((ext_vector_type(4))) float f32x4;
typedef __attribute__((ext_vector_type(4))) unsigned int u32x4;

#define BATCH 8
#define SEQ 1024
#define DMODEL 1024
#define NHEAD 16
#define DHEAD 64
#define QSCALE 0.1803368801f   /* 0.125 * log2(e) */
#define L2E 1.44269504f

// async global->LDS, 16B per lane; LDS dest is wave-uniform base + lane*16
#define GLD16(gptr, lptr)                                                        \
  __builtin_amdgcn_global_load_lds(                                              \
      (const __attribute__((address_space(1))) void*)(gptr),                     \
      (__attribute__((address_space(3))) void*)(lptr), 16, 0, 0)

#define NQKV 8388608u   // B*S*D
#define NW   1048576u   // D*D

__device__ inline unsigned pk2(float a, float b) {
  unsigned short ha = __builtin_bit_cast(unsigned short, (f16)a);
  unsigned short hb = __builtin_bit_cast(unsigned short, (f16)b);
  return ((unsigned)hb << 16) | (unsigned)ha;
}

// ============================================================================
// cast fp32 -> fp16: [q | k | v | Wq | Wk | Wv | Wo] into one flat buffer
// ============================================================================
__global__ __launch_bounds__(256) void cast_all(
    const float* __restrict__ q, const float* __restrict__ k,
    const float* __restrict__ v, const float* __restrict__ wq,
    const float* __restrict__ wk, const float* __restrict__ wv,
    const float* __restrict__ wo, f16* __restrict__ dst) {
  size_t i8 = ((size_t)blockIdx.x * 256 + threadIdx.x) * 8;
  const float* src; size_t off;
  if      (i8 < (size_t)NQKV)            { src = q;  off = 0; }
  else if (i8 < 2ull * NQKV)             { src = k;  off = NQKV; }
  else if (i8 < 3ull * NQKV)             { src = v;  off = 2ull * NQKV; }
  else if (i8 < 3ull * NQKV + NW)        { src = wq; off = 3ull * NQKV; }
  else if (i8 < 3ull * NQKV + 2ull * NW) { src = wk; off = 3ull * NQKV + NW; }
  else if (i8 < 3ull * NQKV + 3ull * NW) { src = wv; off = 3ull * NQKV + 2ull * NW; }
  else                                   { src = wo; off = 3ull * NQKV + 3ull * NW; }
  float4 a = *(const float4*)&src[i8 - off];
  float4 b = *(const float4*)&src[i8 - off + 4];
  f16x8 h;
  h[0] = (f16)a.x; h[1] = (f16)a.y; h[2] = (f16)a.z; h[3] = (f16)a.w;
  h[4] = (f16)b.x; h[5] = (f16)b.y; h[6] = (f16)b.z; h[7] = (f16)b.w;
  *(f16x8*)&dst[i8] = h;
}

// ============================================================================
// Fused QKV projection GEMM, 2-phase pipelined (T3-minimum):
// double-buffered LDS; issue next K-tile's global_load_lds BEFORE computing
// the current one; single barrier per tile (vmcnt drains at the barrier
// after a full compute phase of overlap).
// ============================================================================
__global__ __launch_bounds__(256) void gemm_qkv(const f16* __restrict__ Abase,
                                                const f16* __restrict__ Wqkv,
                                                const float* __restrict__ bq,
                                                const float* __restrict__ bk,
                                                const float* __restrict__ bv,
                                                f16* __restrict__ qp,
                                                f16* __restrict__ kp,
                                                f16* __restrict__ vp) {
  const int K = DMODEL;
  __shared__ f16 As[2][128 * 32];
  __shared__ f16 Bs[2][128 * 32];
  const int t = threadIdx.x;
  const int lane = t & 63, wid = t >> 6;
  const int wm = wid >> 1, wn = wid & 1;
  const int row_l = lane & 15, kgrp = lane >> 4;
  const int m0 = blockIdx.x * 128, n0 = blockIdx.y * 128;
  const int which = n0 >> 10;
  const f16* A = Abase + (size_t)which * NQKV;
  const float* bias = which == 0 ? bq : (which == 1 ? bk : bv);
  f16* outp = which == 0 ? qp : (which == 1 ? kp : vp);
  const int nloc0 = n0 & 1023;
  f32x4 acc[4][4] = {};
  const int srow = t >> 2, scol = (t & 3) * 8;

#define GSTAGE(k0, buf)                                                          \
  {                                                                              \
    _Pragma("unroll")                                                            \
    for (int rr = 0; rr < 2; ++rr) {                                             \
      int row = srow + rr * 64;                                                  \
      char* ab = (char*)&As[buf][0] + (rr * 256 + wid * 64) * 16;                \
      char* bb = (char*)&Bs[buf][0] + (rr * 256 + wid * 64) * 16;                \
      GLD16(&A[(size_t)(m0 + row) * K + (k0) + scol], ab);                       \
      GLD16(&Wqkv[(size_t)(n0 + row) * K + (k0) + scol], bb);                    \
    }                                                                            \
  }

  GSTAGE(0, 0);
  __syncthreads();

  for (int it = 0; it < 32; ++it) {
    int cur = it & 1;
    if (it < 31) GSTAGE((it + 1) * 32, cur ^ 1);
    f16x8 af[4], bf[4];
    #pragma unroll
    for (int i = 0; i < 4; i++) af[i] = *(const f16x8*)&As[cur][(wm * 64 + i * 16 + row_l) * 32 + kgrp * 8];
    #pragma unroll
    for (int j = 0; j < 4; j++) bf[j] = *(const f16x8*)&Bs[cur][(wn * 64 + j * 16 + row_l) * 32 + kgrp * 8];
    #pragma unroll
    for (int i = 0; i < 4; i++)
      #pragma unroll
      for (int j = 0; j < 4; j++)
        acc[i][j] = __builtin_amdgcn_mfma_f32_16x16x32_f16(af[i], bf[j], acc[i][j], 0, 0, 0);
    __syncthreads();
  }

  #pragma unroll
  for (int i = 0; i < 4; i++) {
    int m = m0 + wm * 64 + i * 16 + kgrp * 4;
    #pragma unroll
    for (int j = 0; j < 4; j++) {
      int n = nloc0 + wn * 64 + j * 16 + row_l;
      float bb = bias[n];
      #pragma unroll
      for (int r = 0; r < 4; r++)
        outp[(size_t)(m + r) * DMODEL + n] = (f16)(acc[i][j][r] + bb);
    }
  }
#undef GSTAGE
}

// ============================================================================
// Generic fp16 GEMM (B-transposed), fp32 out, 2-phase pipelined — O projection.
// ============================================================================
__global__ __launch_bounds__(256) void gemm16f(const f16* __restrict__ A,
                                               const f16* __restrict__ W,
                                               const float* __restrict__ bias,
                                               float* __restrict__ C,
                                               int M, int N, int K) {
  __shared__ f16 As[2][128 * 32];
  __shared__ f16 Bs[2][128 * 32];
  const int t = threadIdx.x;
  const int lane = t & 63, wid = t >> 6;
  const int wm = wid >> 1, wn = wid & 1;
  const int row_l = lane & 15, kgrp = lane >> 4;
  const int m0 = blockIdx.x * 128, n0 = blockIdx.y * 128;
  f32x4 acc[4][4] = {};
  const int srow = t >> 2, scol = (t & 3) * 8;
  const int nk = K >> 5;

#define GSTAGE(k0, buf)                                                          \
  {                                                                              \
    _Pragma("unroll")                                                            \
    for (int rr = 0; rr < 2; ++rr) {                                             \
      int row = srow + rr * 64;                                                  \
      char* ab = (char*)&As[buf][0] + (rr * 256 + wid * 64) * 16;                \
      char* bb = (char*)&Bs[buf][0] + (rr * 256 + wid * 64) * 16;                \
      GLD16(&A[(size_t)(m0 + row) * K + (k0) + scol], ab);                       \
      GLD16(&W[(size_t)(n0 + row) * K + (k0) + scol], bb);                       \
    }                                                                            \
  }

  GSTAGE(0, 0);
  __syncthreads();

  for (int it = 0; it < nk; ++it) {
    int cur = it & 1;
    if (it < nk - 1) GSTAGE((it + 1) * 32, cur ^ 1);
    f16x8 af[4], bf[4];
    #pragma unroll
    for (int i = 0; i < 4; i++) af[i] = *(const f16x8*)&As[cur][(wm * 64 + i * 16 + row_l) * 32 + kgrp * 8];
    #pragma unroll
    for (int j = 0; j < 4; j++) bf[j] = *(const f16x8*)&Bs[cur][(wn * 64 + j * 16 + row_l) * 32 + kgrp * 8];
    #pragma unroll
    for (int i = 0; i < 4; i++)
      #pragma unroll
      for (int j = 0; j < 4; j++)
        acc[i][j] = __builtin_amdgcn_mfma_f32_16x16x32_f16(af[i], bf[j], acc[i][j], 0, 0, 0);
    __syncthreads();
  }

  #pragma unroll
  for (int i = 0; i < 4; i++) {
    int m = m0 + wm * 64 + i * 16 + kgrp * 4;
    #pragma unroll
    for (int j = 0; j < 4; j++) {
      int n = n0 + wn * 64 + j * 16 + row_l;
      float bb = bias[n];
      #pragma unroll
      for (int r = 0; r < 4; r++)
        C[(size_t)(m + r) * N + n] = acc[i][j][r] + bb;
    }
  }
#undef GSTAGE
}

// ============================================================================
// RoPE for q (scaled by QSCALE) and k in one launch. fp16 in/out, fp32 math.
// ============================================================================
__global__ __launch_bounds__(256) void rope2(const f16* __restrict__ Xq,
                                             const f16* __restrict__ Xk,
                                             const float* __restrict__ cosb,
                                             const float* __restrict__ sinb,
                                             f16* __restrict__ oq,
                                             f16* __restrict__ ok) {
  int idx = blockIdx.x * 256 + threadIdx.x;      // 0 .. 2*B*S*128
  const int HALFN = BATCH * SEQ * 128;
  bool isq = idx < HALFN;
  if (!isq) idx -= HALFN;
  const f16* X = isq ? Xq : Xk;
  f16* out = isq ? oq : ok;
  float scale = isq ? QSCALE : 1.0f;
  int row = idx >> 7;
  int d4 = (idx & 127) << 2;
  int s = row & (SEQ - 1);
  const f16* xr = X + (size_t)row * DMODEL;
  f16x4 x1 = *(const f16x4*)&xr[d4];
  f16x4 x2 = *(const f16x4*)&xr[d4 + 512];
  float4 c1 = *(const float4*)&cosb[(size_t)s * DMODEL + d4];
  float4 s1 = *(const float4*)&sinb[(size_t)s * DMODEL + d4];
  float4 c2 = *(const float4*)&cosb[(size_t)s * DMODEL + d4 + 512];
  float4 s2 = *(const float4*)&sinb[(size_t)s * DMODEL + d4 + 512];
  f16x4 o1, o2;
  o1[0] = (f16)(scale * ((float)x1[0] * c1.x - (float)x2[0] * s1.x));
  o1[1] = (f16)(scale * ((float)x1[1] * c1.y - (float)x2[1] * s1.y));
  o1[2] = (f16)(scale * ((float)x1[2] * c1.z - (float)x2[2] * s1.z));
  o1[3] = (f16)(scale * ((float)x1[3] * c1.w - (float)x2[3] * s1.w));
  o2[0] = (f16)(scale * ((float)x2[0] * c2.x + (float)x1[0] * s2.x));
  o2[1] = (f16)(scale * ((float)x2[1] * c2.y + (float)x1[1] * s2.y));
  o2[2] = (f16)(scale * ((float)x2[2] * c2.z + (float)x1[2] * s2.z));
  o2[3] = (f16)(scale * ((float)x2[3] * c2.w + (float)x1[3] * s2.w));
  f16* orow = out + (size_t)row * DMODEL;
  *(f16x4*)&orow[d4] = o1;
  *(f16x4*)&orow[d4 + 512] = o2;
}

// ============================================================================
// V transpose (fp16): Vt[b][d][s] = Vp[b][s][d], 64x64 LDS tiles
// ============================================================================
__global__ __launch_bounds__(256) void transv16(const f16* __restrict__ X,
                                                f16* __restrict__ Vt) {
  int bz = blockIdx.x;            // B * 16 * 16 = 2048
  int dt = bz & 15;
  int st = (bz >> 4) & 15;
  int b = bz >> 8;
  int s0 = st * 64, d0 = dt * 64;
  __shared__ f16 tile[64][68];
  int t = threadIdx.x;
  int tr = t >> 4, tc = t & 15;
  #pragma unroll
  for (int i = 0; i < 4; i++) {
    int s_loc = tr + i * 16;
    f16x4 v = *(const f16x4*)&X[((size_t)(b * SEQ + s0 + s_loc)) * DMODEL + d0 + tc * 4];
    *(f16x4*)&tile[s_loc][tc * 4] = v;
  }
  __syncthreads();
  #pragma unroll
  for (int i = 0; i < 4; i++) {
    int d_loc = tr + i * 16;
    f16x4 hv;
    #pragma unroll
    for (int j = 0; j < 4; j++) hv[j] = tile[tc * 4 + j][d_loc];
    *(f16x4*)&Vt[((size_t)(b * DMODEL + d0 + d_loc)) * SEQ + s0 + tc * 4] = hv;
  }
}

// ============================================================================
// Flash attention v4 — swapped operands; shortm computed in-register
// (-|q-kv|, bit-identical to the input matrix); XCD-chunked block swizzle
// so all 16 q-blocks of a (b,h) land on one XCD (K/V working set = 4MB = L2).
// ============================================================================
__global__ __launch_bounds__(256) void attn4(const f16* __restrict__ Q,
                                             const f16* __restrict__ K,
                                             const f16* __restrict__ Vt,
                                             const float* __restrict__ mask,
                                             const float* __restrict__ prior,
                                             f16* __restrict__ out) {
  // XCD swizzle: 2048 blocks = 8 XCDs x 256; chunk of 256 consecutive logical
  // ids (16 full bh-groups) per XCD.
  int bzl = ((blockIdx.x & 7) << 8) + (blockIdx.x >> 3);
  int qb = bzl & 15, bh = bzl >> 4;
  int b = bh >> 4, h = bh & 15;
  int t = threadIdx.x, lane = t & 63, wid = t >> 6;
  int l15 = lane & 15, g = lane >> 4;
  float psc2 = L2E / (1.0f + __expf(-prior[h]));   // sigmoid(prior)*log2e

  const int qrow0 = qb * 64;
  const int qrow = qrow0 + wid * 16 + l15;         // this lane's q
  const f16* Qr = Q + ((size_t)(b * SEQ + qrow)) * DMODEL + h * DHEAD;
  const f16* Kb = K + ((size_t)b * SEQ) * DMODEL + h * DHEAD;
  const f16* Vb = Vt + ((size_t)(b * DMODEL + h * DHEAD)) * SEQ;
  const float* maskb = mask + (size_t)b * SEQ;

  // Q as B-frag: col=q=l15, k=d=g*8+j
  f16x8 aq0 = *(const f16x8*)&Qr[g * 8];
  f16x8 aq1 = *(const f16x8*)&Qr[32 + g * 8];

  __shared__ f16 Ks[2][64 * 64];
  __shared__ f16 Vs[2][64 * 64];

  float mrow = -3.0e38f, lrow = 0.0f;
  f32x4 acco[4] = {};

  // staging coords
  const int slot8 = t & 7;
  const int srow = t >> 3;
  const int gc = ((slot8 ^ (srow & 7)) * 8);
  // bpermute coords
  const int s0 = (g & 1) * 2;
  const int addr0 = (l15 + 16 * s0) * 4;
  const int addr1 = addr0 + 64;
  const bool lowg = (g < 2);
  const int sw = l15 & 7;
  const float qrow_f = (float)qrow;

#define STAGE(tile, buf)                                                          \
  {                                                                               \
    int kb2 = (tile) * 64;                                                        \
    _Pragma("unroll")                                                             \
    for (int rr = 0; rr < 2; ++rr) {                                              \
      int row = srow + rr * 32;                                                   \
      char* kdst = (char*)&Ks[buf][0] + rr * 4096 + wid * 1024;                   \
      char* vdst = (char*)&Vs[buf][0] + rr * 4096 + wid * 1024;                   \
      GLD16(&Kb[(size_t)(kb2 + row) * DMODEL + gc], kdst);                        \
      GLD16(&Vb[(size_t)row * SEQ + kb2 + gc], vdst);                             \
    }                                                                             \
  }

  STAGE(0, 0);
  __syncthreads();

  for (int it = 0; it < 16; ++it) {
    int cur = it & 1;
    if (it < 15) STAGE(it + 1, cur ^ 1);
    int kb = it * 64;
    const f16* ks = &Ks[cur][0];
    const f16* vs = &Vs[cur][0];

    // --- QK^T (swapped): sc[hh] = S^T[kv=g*4+r+16hh][q=l15] ---
    f32x4 sc[4];
    #pragma unroll
    for (int hh = 0; hh < 4; ++hh) {
      int kr = l15 + 16 * hh;
      f16x8 kf0 = *(const f16x8*)&ks[kr * 64 + ((g ^ sw) * 8)];
      f16x8 kf1 = *(const f16x8*)&ks[kr * 64 + (((4 + g) ^ sw) * 8)];
      f32x4 z = {};
      z = __builtin_amdgcn_mfma_f32_16x16x32_f16(kf0, aq0, z, 0, 0, 0);
      z = __builtin_amdgcn_mfma_f32_16x16x32_f16(kf1, aq1, z, 0, 0, 0);
      sc[hh] = z;
    }

    // --- bias: s = sc + mask*log2e + psc2 * (-|qrow - kv|) (computed) ---
    float s[4][4];
    #pragma unroll
    for (int hh = 0; hh < 4; ++hh) {
      int kv = kb + hh * 16 + g * 4;
      float4 mk = *(const float4*)&maskb[kv];
      #pragma unroll
      for (int r = 0; r < 4; ++r) {
        float smv = -fabsf(qrow_f - (float)(kv + r));
        float mkr = r == 0 ? mk.x : (r == 1 ? mk.y : (r == 2 ? mk.z : mk.w));
        s[hh][r] = fmaf(L2E, mkr, fmaf(psc2, smv, sc[hh][r]));
      }
    }

    // --- online softmax (per-lane scalar m/l) ---
    float pmax = fmaxf(fmaxf(fmaxf(s[0][0], s[0][1]), fmaxf(s[0][2], s[0][3])),
                       fmaxf(fmaxf(s[1][0], s[1][1]), fmaxf(s[1][2], s[1][3])));
    pmax = fmaxf(pmax, fmaxf(fmaxf(fmaxf(s[2][0], s[2][1]), fmaxf(s[2][2], s[2][3])),
                             fmaxf(fmaxf(s[3][0], s[3][1]), fmaxf(s[3][2], s[3][3]))));
    pmax = fmaxf(pmax, __shfl_xor(pmax, 16));
    pmax = fmaxf(pmax, __shfl_xor(pmax, 32));
    if (__any(pmax > mrow)) {
      float mnew = fmaxf(mrow, pmax);
      float fs = exp2f(mrow - mnew);
      lrow *= fs;
      #pragma unroll
      for (int t2 = 0; t2 < 4; ++t2)
        #pragma unroll
        for (int r = 0; r < 4; ++r) acco[t2][r] *= fs;
      mrow = mnew;
    }
    float p[4][4];
    #pragma unroll
    for (int hh = 0; hh < 4; ++hh)
      #pragma unroll
      for (int r = 0; r < 4; ++r) p[hh][r] = exp2f(s[hh][r] - mrow);
    float rs = ((p[0][0] + p[0][1]) + (p[0][2] + p[0][3])) +
               ((p[1][0] + p[1][1]) + (p[1][2] + p[1][3])) +
               ((p[2][0] + p[2][1]) + (p[2][2] + p[2][3])) +
               ((p[3][0] + p[3][1]) + (p[3][2] + p[3][3]));
    rs += __shfl_xor(rs, 16);
    rs += __shfl_xor(rs, 32);
    lrow += rs;

    // --- pack P to f16 + in-register redistribution to B-frag layout ---
    unsigned cfr[2][4];
    #pragma unroll
    for (int half = 0; half < 2; ++half) {
      unsigned a0 = pk2(p[half * 2][0], p[half * 2][1]);
      unsigned a1 = pk2(p[half * 2][2], p[half * 2][3]);
      unsigned b0 = pk2(p[half * 2 + 1][0], p[half * 2 + 1][1]);
      unsigned b1 = pk2(p[half * 2 + 1][2], p[half * 2 + 1][3]);
      int ta0 = __builtin_amdgcn_ds_bpermute(addr0, (int)a0);
      int ta1 = __builtin_amdgcn_ds_bpermute(addr0, (int)a1);
      int tb0 = __builtin_amdgcn_ds_bpermute(addr0, (int)b0);
      int tb1 = __builtin_amdgcn_ds_bpermute(addr0, (int)b1);
      int ua0 = __builtin_amdgcn_ds_bpermute(addr1, (int)a0);
      int ua1 = __builtin_amdgcn_ds_bpermute(addr1, (int)a1);
      int ub0 = __builtin_amdgcn_ds_bpermute(addr1, (int)b0);
      int ub1 = __builtin_amdgcn_ds_bpermute(addr1, (int)b1);
      cfr[half][0] = (unsigned)(lowg ? ta0 : tb0);
      cfr[half][1] = (unsigned)(lowg ? ta1 : tb1);
      cfr[half][2] = (unsigned)(lowg ? ua0 : ub0);
      cfr[half][3] = (unsigned)(lowg ? ua1 : ub1);
    }

    // --- PV (swapped): acco[t2] covers dv = t2*16 + g*4 + r ---
    #pragma unroll
    for (int half = 0; half < 2; ++half) {
      u32x4 cc; cc[0] = cfr[half][0]; cc[1] = cfr[half][1];
      cc[2] = cfr[half][2]; cc[3] = cfr[half][3];
      f16x8 pf = __builtin_bit_cast(f16x8, cc);
      #pragma unroll
      for (int t2 = 0; t2 < 4; ++t2) {
        int vr = t2 * 16 + l15;
        f16x8 vf = *(const f16x8*)&vs[vr * 64 + (((half * 4 + g) ^ sw) * 8)];
        acco[t2] = __builtin_amdgcn_mfma_f32_16x16x32_f16(vf, pf, acco[t2], 0, 0, 0);
      }
    }
    __syncthreads();
  }

  // --- epilogue: O^T -> LDS transpose (swizzled) -> coalesced f16 store ---
  float inv = 1.0f / lrow;
  f16* Pw = &Ks[0][0] + wid * 1024;   // wave-private 16q x 64dv slice
  #pragma unroll
  for (int t2 = 0; t2 < 4; ++t2) {
    f16x4 o;
    #pragma unroll
    for (int r = 0; r < 4; ++r) o[r] = (f16)(acco[t2][r] * inv);
    int sl = t2 * 4 + g;              // 8B slot = dv>>2
    int s16 = sl >> 1, p8 = sl & 1;
    int swz = s16 ^ sw;
    *(f16x4*)&Pw[l15 * 64 + swz * 8 + p8 * 4] = o;
  }
  __syncthreads();
  int rq = lane >> 3;                 // 0..7
  int cs = lane & 7;                  // real 16B slot (dv block)
  #pragma unroll
  for (int half = 0; half < 2; ++half) {
    int q_loc = rq + half * 8;
    int swz = cs ^ (q_loc & 7);
    f16x8 vv = *(const f16x8*)&Pw[q_loc * 64 + swz * 8];
    int qg = qrow0 + wid * 16 + q_loc;
    *(f16x8*)&out[((size_t)(b * SEQ + qg)) * DMODEL + h * DHEAD + cs * 8] = vv;
  }
#undef STAGE
}

// ============================================================================
extern "C" void kernel_launch(void* const* d_in, const int* in_sizes, int n_in,
                              void* d_out, int out_size, void* d_ws, size_t ws_size,
                              hipStream_t stream) {
  const float* q      = (const float*)d_in[0];
  const float* k      = (const float*)d_in[1];
  const float* v      = (const float*)d_in[2];
  const float* cosb   = (const float*)d_in[3];
  const float* sinb   = (const float*)d_in[4];
  const float* mask   = (const float*)d_in[5];
  const float* Wq     = (const float*)d_in[7];
  const float* bq     = (const float*)d_in[8];
  const float* Wk     = (const float*)d_in[9];
  const float* bk     = (const float*)d_in[10];
  const float* Wv     = (const float*)d_in[11];
  const float* bv     = (const float*)d_in[12];
  const float* Wo     = (const float*)d_in[13];
  const float* bo     = (const float*)d_in[14];
  const float* prior  = (const float*)d_in[15];
  float* outp = (float*)d_out;

  const size_t M = (size_t)BATCH * SEQ;             // 8192
  f16* ws16 = (f16*)d_ws;
  f16* qf   = ws16;                                 // casted inputs (contiguous)
  f16* kf   = ws16 + (size_t)NQKV;
  f16* vf   = ws16 + 2ull * NQKV;
  f16* Wqkv = ws16 + 3ull * NQKV;                   // [Wq|Wk|Wv] contiguous
  f16* Wof  = Wqkv + 3ull * NW;
  f16* qp   = ws16 + 3ull * NQKV + 4ull * NW;       // projection outputs
  f16* kp   = qp + NQKV;
  f16* vp   = kp + NQKV;
  // aliases (sources dead by the time these are written)
  f16* qro = qf;
  f16* kro = kf;
  f16* vt  = vf;
  f16* cat = qp;

  cast_all<<<(3u * NQKV + 4u * NW) / 8 / 256, 256, 0, stream>>>(q, k, v, Wq, Wk, Wv, Wo, ws16);

  dim3 qkv_grid(M / 128, 3 * DMODEL / 128);         // 64 x 24
  gemm_qkv<<<qkv_grid, 256, 0, stream>>>(qf, Wqkv, bq, bk, bv, qp, kp, vp);

  rope2<<<2 * (int)(M * 128 / 256), 256, 0, stream>>>(qp, kp, cosb, sinb, qro, kro);
  transv16<<<BATCH * 16 * 16, 256, 0, stream>>>(vp, vt);

  attn4<<<BATCH * NHEAD * (SEQ / 64), 256, 0, stream>>>(qro, kro, vt, mask, prior, cat);

  dim3 o_grid(M / 128, DMODEL / 128);               // 64 x 8
  gemm16f<<<o_grid, 256, 0, stream>>>(cat, Wof, bo, outp, (int)M, DMODEL, DMODEL);
}